// Round 7
// baseline (218.999 us; speedup 1.0000x reference)
//
#include <hip/hip_runtime.h>
#include <math.h>

// Problem constants (fixed by reference setup_inputs)
#define BSZ   16
#define NA    3
#define NH    80
#define NW    80
#define NC    80
#define HW    (NH * NW)                 // 6400
#define CELLS (BSZ * NA * NH * NW)      // 307200
#define EPSL  1e-07f
#define BLK   256

#define CLS_CB 64                       // cells per block
#define NBLK   (CELLS / CLS_CB)         // 4800 blocks, one fused dispatch
#define PADS   65                       // LDS row stride (words) for tl2[ch][cell]

// ws layout (floats, SoA): [j*NBLK + b], j = 0:xy 1:wh 2:iou 3:conf 4:cls
// counter (uint) at byte offset CNT_OFF
#define CNT_OFF (5 * NBLK * 4)          // 96000

#define L2E 1.4426950408889634f
#define LN2 0.6931471805599453f

__device__ __forceinline__ float fexp2(float x) { return __builtin_amdgcn_exp2f(x); }
__device__ __forceinline__ float flog2(float x) { return __builtin_amdgcn_logf(x); }
__device__ __forceinline__ float frcp(float x)  { return __builtin_amdgcn_rcpf(x); }

// max(z,0) - z*t + log1p(exp(-|z|)) via HW exp2/log2
__device__ __forceinline__ float bce_fast(float z, float t) {
    const float e  = fexp2(-fabsf(z) * L2E);
    const float sp = LN2 * flog2(1.0f + e);
    return fmaxf(z, 0.0f) - z * t + sp;
}

__device__ __forceinline__ float sigmoid_fast(float z) {
    return frcp(1.0f + fexp2(-z * L2E));
}

__global__ __launch_bounds__(BLK, 6) void yolo_loss_fused(
    const float* __restrict__ input,
    const float* __restrict__ mask,
    const float* __restrict__ obj_mask,
    const float* __restrict__ tx,
    const float* __restrict__ ty,
    const float* __restrict__ tw,
    const float* __restrict__ th,
    const float* __restrict__ tgt_scale,
    const float* __restrict__ tcls,
    float* __restrict__ ws,
    unsigned int* __restrict__ cnt,
    float* __restrict__ out)
{
    __shared__ float tl2[NC * PADS];            // [channel][cell], 20.8 KB
    __shared__ float red[4];
    __shared__ int   lastFlag;

    const int tid  = threadIdx.x;
    const int lane = tid & 63;
    const int wid  = tid >> 6;
    const int bid  = blockIdx.x;

    const int B0    = bid * CLS_CB;             // first cell (64 | HW)
    const int plane = B0 / HW;
    const int hw0   = B0 % HW;
    const float* pbase = input + (size_t)plane * (5 + NC) * HW + hw0;

    // ---- Phase 1: stage 64*320B tcls slab -> LDS transposed (contiguous reads)
    const float* tslab = tcls + (size_t)B0 * NC;
    float4 stg[5];
    #pragma unroll
    for (int k = 0; k < 5; ++k)
        stg[k] = *(const float4*)(tslab + 4 * (size_t)(tid + BLK * k));

    // ---- Box loads for this block's 64 cells: wave 0, lane = cell (coalesced)
    float bzx, bzy, bpw, bph, bzc, bm, bom, bgx, bgy, bgw, bgh, bts;
    if (wid == 0) {
        bzx = pbase[0 * HW + lane];
        bzy = pbase[1 * HW + lane];
        bpw = pbase[2 * HW + lane];
        bph = pbase[3 * HW + lane];
        bzc = pbase[4 * HW + lane];
        bm  = mask[B0 + lane];
        bom = obj_mask[B0 + lane];
        bgx = tx[B0 + lane];
        bgy = ty[B0 + lane];
        bgw = tw[B0 + lane];
        bgh = th[B0 + lane];
        bts = tgt_scale[B0 + lane];
    }

    #pragma unroll
    for (int k = 0; k < 5; ++k) {
        const int c  = tid + BLK * k;           // 16B-chunk id, 0..1279
        const int qc = c / 20;                  // cell in block
        const int g  = c % 20;                  // chunk within cell
        tl2[(4 * g + 0) * PADS + qc] = stg[k].x;
        tl2[(4 * g + 1) * PADS + qc] = stg[k].y;
        tl2[(4 * g + 2) * PADS + qc] = stg[k].z;
        tl2[(4 * g + 3) * PADS + qc] = stg[k].w;
    }
    __syncthreads();

    // ---- Phase 2: class BCE. Thread (q,p): channels [20p,20p+20) of cell B0+q
    const int q = tid >> 2;
    const int p = tid & 3;
    const float* zb = pbase + (size_t)(5 + 20 * p) * HW + q;
    float z[20];
    #pragma unroll
    for (int i = 0; i < 20; ++i)
        z[i] = zb[(size_t)i * HW];              // 20 loads in flight
    float acc = 0.f;
    #pragma unroll
    for (int i = 0; i < 20; ++i)
        acc += bce_fast(z[i], tl2[(20 * p + i) * PADS + q]);
    float vcls = mask[B0 + q] * acc;

    #pragma unroll
    for (int off = 32; off > 0; off >>= 1)
        vcls += __shfl_down(vcls, off, 64);
    if (lane == 0) red[wid] = vcls;

    // ---- Box compute on wave 0 (loads issued pre-barrier, long since landed)
    float s_xy = 0.f, s_wh = 0.f, s_iou = 0.f, s_conf = 0.f;
    if (wid == 0) {
        const float x = sigmoid_fast(bzx);
        const float y = sigmoid_fast(bzy);

        s_xy   = bts * (fabsf(x - bgx) + fabsf(y - bgy));
        s_wh   = bts * (fabsf(bpw - bgw) + fabsf(bph - bgh));
        s_conf = bom * bce_fast(bzc, bm);

        const float p_x1 = x - bpw * 0.5f, p_x2 = x + bpw * 0.5f;
        const float p_y1 = y - bph * 0.5f, p_y2 = y + bph * 0.5f;
        const float g_x1 = bgx - bgw * 0.5f, g_x2 = bgx + bgw * 0.5f;
        const float g_y1 = bgy - bgh * 0.5f, g_y2 = bgy + bgh * 0.5f;

        const float iw = fmaxf(fminf(p_x2, g_x2) - fmaxf(p_x1, g_x1), 0.0f);
        const float ih = fmaxf(fminf(p_y2, g_y2) - fmaxf(p_y1, g_y1), 0.0f);
        const float inter = iw * ih;
        const float uni   = bpw * bph + bgw * bgh - inter + EPSL;
        const float iou   = inter * frcp(uni);

        const float cw = fmaxf(p_x2, g_x2) - fminf(p_x1, g_x1);
        const float ch = fmaxf(p_y2, g_y2) - fminf(p_y1, g_y1);
        const float c2 = cw * cw + ch * ch + EPSL;
        const float rho2 = (x - bgx) * (x - bgx) + (y - bgy) * (y - bgy);

        const float da = atanf(bgw * frcp(bgh + EPSL))
                       - atanf(bpw * frcp(bph + EPSL));
        const float v  = (4.0f / (float)(M_PI * M_PI)) * da * da;
        const float alpha = v * frcp(v - iou + 1.0f + EPSL);

        const float lbox = 1.0f - (iou - (rho2 * frcp(c2) + v * alpha));
        s_iou = bm * bts * lbox;

        #pragma unroll
        for (int off = 32; off > 0; off >>= 1) {
            s_xy   += __shfl_down(s_xy,   off, 64);
            s_wh   += __shfl_down(s_wh,   off, 64);
            s_iou  += __shfl_down(s_iou,  off, 64);
            s_conf += __shfl_down(s_conf, off, 64);
        }
    }
    __syncthreads();

    // ---- Publish partials (SoA), then last-block detection
    if (tid == 0) {
        ws[0 * NBLK + bid] = s_xy;
        ws[1 * NBLK + bid] = s_wh;
        ws[2 * NBLK + bid] = s_iou;
        ws[3 * NBLK + bid] = s_conf;
        ws[4 * NBLK + bid] = red[0] + red[1] + red[2] + red[3];
        __threadfence();
        const unsigned int old = atomicAdd(cnt, 1u);
        lastFlag = (old == (unsigned int)(NBLK - 1));
    }
    __syncthreads();

    // ---- Last block: deterministic final reduction (fixed order)
    if (lastFlag) {
        __threadfence();
        const float scale[5] = { 1.0f / (BSZ * BSZ), 1.0f / (BSZ * BSZ),
                                 1.0f / BSZ, 1.0f / BSZ, 1.0f / BSZ };
        for (int j = 0; j < 5; ++j) {
            float v = 0.f;
            for (int i = tid; i < NBLK; i += BLK)
                v += __hip_atomic_load(&ws[(size_t)j * NBLK + i],
                                       __ATOMIC_RELAXED, __HIP_MEMORY_SCOPE_AGENT);
            #pragma unroll
            for (int off = 32; off > 0; off >>= 1)
                v += __shfl_down(v, off, 64);
            __syncthreads();                    // red[] reuse safety
            if (lane == 0) red[wid] = v;
            __syncthreads();
            if (tid == 0)
                out[j] = (red[0] + red[1] + red[2] + red[3]) * scale[j];
        }
    }
}

extern "C" void kernel_launch(void* const* d_in, const int* in_sizes, int n_in,
                              void* d_out, int out_size, void* d_ws, size_t ws_size,
                              hipStream_t stream) {
    const float* input     = (const float*)d_in[0];
    const float* mask      = (const float*)d_in[1];
    const float* obj_mask  = (const float*)d_in[2];
    const float* tx        = (const float*)d_in[3];
    const float* ty        = (const float*)d_in[4];
    const float* tw        = (const float*)d_in[5];
    const float* th        = (const float*)d_in[6];
    const float* tgt_scale = (const float*)d_in[7];
    const float* tcls      = (const float*)d_in[8];
    float* out = (float*)d_out;
    float* ws  = (float*)d_ws;                    // needs 96004 bytes
    unsigned int* cnt = (unsigned int*)((char*)d_ws + CNT_OFF);

    hipMemsetAsync(cnt, 0, sizeof(unsigned int), stream);
    yolo_loss_fused<<<NBLK, BLK, 0, stream>>>(
        input, mask, obj_mask, tx, ty, tw, th, tgt_scale, tcls, ws, cnt, out);
}

// Round 8
// 60.661 us; speedup vs baseline: 3.6102x; 3.6102x over previous
//
#include <hip/hip_runtime.h>
#include <math.h>

// Problem constants (fixed by reference setup_inputs)
#define BSZ   16
#define NA    3
#define NH    80
#define NW    80
#define NC    80
#define HW    (NH * NW)                 // 6400
#define CELLS (BSZ * NA * NH * NW)      // 307200
#define EPSL  1e-07f
#define BLK   256

#define CLS_CB 64                       // cells per block
#define NBLK   (CELLS / CLS_CB)         // 4800 blocks, one fused dispatch
#define PADS   65                       // LDS row stride (words) for tl2[ch][cell]

// ws layout (floats, SoA): [j*NBLK + b], j = 0:xy 1:wh 2:iou 3:conf 4:cls
#define L2E 1.4426950408889634f
#define LN2 0.6931471805599453f

__device__ __forceinline__ float fexp2(float x) { return __builtin_amdgcn_exp2f(x); }
__device__ __forceinline__ float flog2(float x) { return __builtin_amdgcn_logf(x); }
__device__ __forceinline__ float frcp(float x)  { return __builtin_amdgcn_rcpf(x); }

// max(z,0) - z*t + log1p(exp(-|z|)) via HW exp2/log2
__device__ __forceinline__ float bce_fast(float z, float t) {
    const float e  = fexp2(-fabsf(z) * L2E);
    const float sp = LN2 * flog2(1.0f + e);
    return fmaxf(z, 0.0f) - z * t + sp;
}

__device__ __forceinline__ float sigmoid_fast(float z) {
    return frcp(1.0f + fexp2(-z * L2E));
}

__global__ __launch_bounds__(BLK, 7) void yolo_loss_fused(
    const float* __restrict__ input,
    const float* __restrict__ mask,
    const float* __restrict__ obj_mask,
    const float* __restrict__ tx,
    const float* __restrict__ ty,
    const float* __restrict__ tw,
    const float* __restrict__ th,
    const float* __restrict__ tgt_scale,
    const float* __restrict__ tcls,
    float* __restrict__ ws)
{
    __shared__ float tl2[NC * PADS];            // [channel][cell], 20.8 KB
    __shared__ float red[4];

    const int tid  = threadIdx.x;
    const int lane = tid & 63;
    const int wid  = tid >> 6;
    const int bid  = blockIdx.x;

    const int B0    = bid * CLS_CB;             // first cell (64 | HW)
    const int plane = B0 / HW;
    const int hw0   = B0 % HW;
    const float* pbase = input + (size_t)plane * (5 + NC) * HW + hw0;

    // ---- Phase 1: stage 64*320B tcls slab -> LDS transposed (contiguous reads)
    const float* tslab = tcls + (size_t)B0 * NC;
    float4 stg[5];
    #pragma unroll
    for (int k = 0; k < 5; ++k)
        stg[k] = *(const float4*)(tslab + 4 * (size_t)(tid + BLK * k));

    // ---- Box loads for this block's 64 cells: wave 0, lane = cell (coalesced)
    float bzx, bzy, bpw, bph, bzc, bm, bom, bgx, bgy, bgw, bgh, bts;
    if (wid == 0) {
        bzx = pbase[0 * HW + lane];
        bzy = pbase[1 * HW + lane];
        bpw = pbase[2 * HW + lane];
        bph = pbase[3 * HW + lane];
        bzc = pbase[4 * HW + lane];
        bm  = mask[B0 + lane];
        bom = obj_mask[B0 + lane];
        bgx = tx[B0 + lane];
        bgy = ty[B0 + lane];
        bgw = tw[B0 + lane];
        bgh = th[B0 + lane];
        bts = tgt_scale[B0 + lane];
    }

    #pragma unroll
    for (int k = 0; k < 5; ++k) {
        const int c  = tid + BLK * k;           // 16B-chunk id, 0..1279
        const int qc = c / 20;                  // cell in block
        const int g  = c % 20;                  // chunk within cell
        tl2[(4 * g + 0) * PADS + qc] = stg[k].x;
        tl2[(4 * g + 1) * PADS + qc] = stg[k].y;
        tl2[(4 * g + 2) * PADS + qc] = stg[k].z;
        tl2[(4 * g + 3) * PADS + qc] = stg[k].w;
    }
    __syncthreads();

    // ---- Phase 2: class BCE. Thread (q,p): channels [20p,20p+20) of cell B0+q
    const int q = tid >> 2;
    const int p = tid & 3;
    const float* zb = pbase + (size_t)(5 + 20 * p) * HW + q;
    float z[20];
    #pragma unroll
    for (int i = 0; i < 20; ++i)
        z[i] = zb[(size_t)i * HW];              // 20 loads in flight
    float acc = 0.f;
    #pragma unroll
    for (int i = 0; i < 20; ++i)
        acc += bce_fast(z[i], tl2[(20 * p + i) * PADS + q]);
    float vcls = mask[B0 + q] * acc;

    #pragma unroll
    for (int off = 32; off > 0; off >>= 1)
        vcls += __shfl_down(vcls, off, 64);
    if (lane == 0) red[wid] = vcls;

    // ---- Box compute on wave 0 (loads issued pre-barrier, long since landed)
    float s_xy = 0.f, s_wh = 0.f, s_iou = 0.f, s_conf = 0.f;
    if (wid == 0) {
        const float x = sigmoid_fast(bzx);
        const float y = sigmoid_fast(bzy);

        s_xy   = bts * (fabsf(x - bgx) + fabsf(y - bgy));
        s_wh   = bts * (fabsf(bpw - bgw) + fabsf(bph - bgh));
        s_conf = bom * bce_fast(bzc, bm);

        const float p_x1 = x - bpw * 0.5f, p_x2 = x + bpw * 0.5f;
        const float p_y1 = y - bph * 0.5f, p_y2 = y + bph * 0.5f;
        const float g_x1 = bgx - bgw * 0.5f, g_x2 = bgx + bgw * 0.5f;
        const float g_y1 = bgy - bgh * 0.5f, g_y2 = bgy + bgh * 0.5f;

        const float iw = fmaxf(fminf(p_x2, g_x2) - fmaxf(p_x1, g_x1), 0.0f);
        const float ih = fmaxf(fminf(p_y2, g_y2) - fmaxf(p_y1, g_y1), 0.0f);
        const float inter = iw * ih;
        const float uni   = bpw * bph + bgw * bgh - inter + EPSL;
        const float iou   = inter * frcp(uni);

        const float cw = fmaxf(p_x2, g_x2) - fminf(p_x1, g_x1);
        const float ch = fmaxf(p_y2, g_y2) - fminf(p_y1, g_y1);
        const float c2 = cw * cw + ch * ch + EPSL;
        const float rho2 = (x - bgx) * (x - bgx) + (y - bgy) * (y - bgy);

        const float da = atanf(bgw * frcp(bgh + EPSL))
                       - atanf(bpw * frcp(bph + EPSL));
        const float v  = (4.0f / (float)(M_PI * M_PI)) * da * da;
        const float alpha = v * frcp(v - iou + 1.0f + EPSL);

        const float lbox = 1.0f - (iou - (rho2 * frcp(c2) + v * alpha));
        s_iou = bm * bts * lbox;

        #pragma unroll
        for (int off = 32; off > 0; off >>= 1) {
            s_xy   += __shfl_down(s_xy,   off, 64);
            s_wh   += __shfl_down(s_wh,   off, 64);
            s_iou  += __shfl_down(s_iou,  off, 64);
            s_conf += __shfl_down(s_conf, off, 64);
        }
    }
    __syncthreads();

    // ---- Publish partials (SoA)
    if (tid == 0) {
        ws[0 * NBLK + bid] = s_xy;
        ws[1 * NBLK + bid] = s_wh;
        ws[2 * NBLK + bid] = s_iou;
        ws[3 * NBLK + bid] = s_conf;
        ws[4 * NBLK + bid] = red[0] + red[1] + red[2] + red[3];
    }
}

// Deterministic final reduction: one block, fixed order -> identical every replay.
__global__ __launch_bounds__(BLK) void yolo_loss_final(
    const float* __restrict__ ws, float* __restrict__ out)
{
    __shared__ float red[4];
    const int lane = threadIdx.x & 63;
    const int wid  = threadIdx.x >> 6;
    const float scale[5] = { 1.0f / (BSZ * BSZ), 1.0f / (BSZ * BSZ),
                             1.0f / BSZ, 1.0f / BSZ, 1.0f / BSZ };

    for (int j = 0; j < 5; ++j) {
        float v = 0.f;
        for (int i = threadIdx.x; i < NBLK; i += BLK)
            v += ws[(size_t)j * NBLK + i];
        #pragma unroll
        for (int off = 32; off > 0; off >>= 1)
            v += __shfl_down(v, off, 64);
        if (lane == 0) red[wid] = v;
        __syncthreads();
        if (threadIdx.x == 0)
            out[j] = (red[0] + red[1] + red[2] + red[3]) * scale[j];
        __syncthreads();
    }
}

extern "C" void kernel_launch(void* const* d_in, const int* in_sizes, int n_in,
                              void* d_out, int out_size, void* d_ws, size_t ws_size,
                              hipStream_t stream) {
    const float* input     = (const float*)d_in[0];
    const float* mask      = (const float*)d_in[1];
    const float* obj_mask  = (const float*)d_in[2];
    const float* tx        = (const float*)d_in[3];
    const float* ty        = (const float*)d_in[4];
    const float* tw        = (const float*)d_in[5];
    const float* th        = (const float*)d_in[6];
    const float* tgt_scale = (const float*)d_in[7];
    const float* tcls      = (const float*)d_in[8];
    float* out = (float*)d_out;
    float* ws  = (float*)d_ws;                    // needs 5*4800*4 = 96000 bytes

    yolo_loss_fused<<<NBLK, BLK, 0, stream>>>(
        input, mask, obj_mask, tx, ty, tw, th, tgt_scale, tcls, ws);
    yolo_loss_final<<<1, BLK, 0, stream>>>(ws, out);
}

// Round 9
// 45.158 us; speedup vs baseline: 4.8496x; 1.3433x over previous
//
#include <hip/hip_runtime.h>
#include <math.h>

// Problem constants (fixed by reference setup_inputs)
#define BSZ   16
#define NA    3
#define NH    80
#define NW    80
#define NC    80
#define HW    (NH * NW)                 // 6400
#define CELLS (BSZ * NA * NH * NW)      // 307200
#define EPSL  1e-07f
#define BLK   256

// Class path: 64 cells per 256-thread block, 4 lanes per cell (20 ch each).
#define CLS_CB   64
#define NBLK_CLS (CELLS / CLS_CB)       // 4800
#define NBLK_BOX (CELLS / BLK)          // 1200
#define NBLK_TOT (NBLK_CLS + NBLK_BOX)  // 6000
#define PADS     65                     // LDS row stride (words) for tl2[ch][cell]

// ws layout: [0 .. NBLK_BOX*4)            box partials (xy, wh, iou, conf)
//            [WS_CLS .. WS_CLS+NBLK_CLS)  class partials
#define WS_CLS (NBLK_BOX * 4)           // 4800

#define L2E 1.4426950408889634f
#define LN2 0.6931471805599453f

__device__ __forceinline__ float fexp2(float x) { return __builtin_amdgcn_exp2f(x); }
__device__ __forceinline__ float flog2(float x) { return __builtin_amdgcn_logf(x); }
__device__ __forceinline__ float frcp(float x)  { return __builtin_amdgcn_rcpf(x); }

// max(z,0) - z*t + log1p(exp(-|z|)) via HW exp2/log2
__device__ __forceinline__ float bce_fast(float z, float t) {
    const float e  = fexp2(-fabsf(z) * L2E);
    const float sp = LN2 * flog2(1.0f + e);
    return fmaxf(z, 0.0f) - z * t + sp;
}

__device__ __forceinline__ float sigmoid_fast(float z) {
    return frcp(1.0f + fexp2(-z * L2E));
}

__global__ __launch_bounds__(BLK, 6) void yolo_loss_main(
    const float* __restrict__ input,
    const float* __restrict__ mask,
    const float* __restrict__ obj_mask,
    const float* __restrict__ tx,
    const float* __restrict__ ty,
    const float* __restrict__ tw,
    const float* __restrict__ th,
    const float* __restrict__ tgt_scale,
    const float* __restrict__ tcls,
    float* __restrict__ ws)
{
    __shared__ float red[4][4];
    const int tid  = threadIdx.x;
    const int lane = tid & 63;
    const int wid  = tid >> 6;
    const int bid  = blockIdx.x;

    if (bid < NBLK_CLS) {
        // ---- class-BCE: 64 cells/block, tcls staged via LDS (contiguous) ----
        __shared__ float tl2[NC * PADS];            // [channel][cell], 20.8 KB
        const int B0    = bid * CLS_CB;             // first cell (64 | HW)
        const int plane = B0 / HW;
        const int hw0   = B0 % HW;

        // Issue tcls staging loads (5 float4, wave-contiguous)
        const float* tslab = tcls + (size_t)B0 * NC;
        float4 stg[5];
        #pragma unroll
        for (int k = 0; k < 5; ++k)
            stg[k] = *(const float4*)(tslab + 4 * (size_t)(tid + BLK * k));

        // HOISTED: issue all 20 z loads + mask load BEFORE LDS stores/barrier,
        // so ~26 loads are in flight while staging and the barrier drain.
        const int q = tid >> 2;
        const int p = tid & 3;
        const float* zb = input + (size_t)plane * (5 + NC) * HW
                        + (size_t)(5 + 20 * p) * HW + hw0 + q;
        float z[20];
        #pragma unroll
        for (int i = 0; i < 20; ++i)
            z[i] = zb[(size_t)i * HW];
        const float mq = mask[B0 + q];

        // LDS transposed stores (consume stg)
        #pragma unroll
        for (int k = 0; k < 5; ++k) {
            const int c  = tid + BLK * k;           // 16B-chunk id, 0..1279
            const int qc = c / 20;                  // cell in block
            const int g  = c % 20;                  // chunk within cell
            tl2[(4 * g + 0) * PADS + qc] = stg[k].x;
            tl2[(4 * g + 1) * PADS + qc] = stg[k].y;
            tl2[(4 * g + 2) * PADS + qc] = stg[k].z;
            tl2[(4 * g + 3) * PADS + qc] = stg[k].w;
        }
        __syncthreads();

        // Phase 2: thread (q, p) does channels [20p, 20p+20) of cell B0+q
        float acc = 0.f;
        #pragma unroll
        for (int i = 0; i < 20; ++i)
            acc += bce_fast(z[i], tl2[(20 * p + i) * PADS + q]);
        float v = mq * acc;

        #pragma unroll
        for (int off = 32; off > 0; off >>= 1)
            v += __shfl_down(v, off, 64);
        if (lane == 0) red[wid][0] = v;
        __syncthreads();
        if (tid == 0)
            ws[WS_CLS + bid] = red[0][0] + red[1][0] + red[2][0] + red[3][0];

    } else {
        // ------- box/conf/CIOU path: one cell per thread (coalesced) -------
        const int bbid  = bid - NBLK_CLS;
        const int cell  = bbid * BLK + tid;
        const int hw    = cell % HW;
        const int plane = cell / HW;

        const float* pbase = input + (size_t)plane * (5 + NC) * HW + hw;

        const float zx = pbase[0 * HW];
        const float zy = pbase[1 * HW];
        const float pw = pbase[2 * HW];
        const float ph = pbase[3 * HW];
        const float zc = pbase[4 * HW];

        const float m  = mask[cell];
        const float om = obj_mask[cell];
        const float gx = tx[cell];
        const float gy = ty[cell];
        const float gw = tw[cell];
        const float gh = th[cell];
        const float ts = tgt_scale[cell];

        const float x = sigmoid_fast(zx);
        const float y = sigmoid_fast(zy);

        float s_xy  = ts * (fabsf(x - gx) + fabsf(y - gy));
        float s_wh  = ts * (fabsf(pw - gw) + fabsf(ph - gh));
        float s_conf = om * bce_fast(zc, m);
        float s_iou;
        {
            const float p_x1 = x - pw * 0.5f, p_x2 = x + pw * 0.5f;
            const float p_y1 = y - ph * 0.5f, p_y2 = y + ph * 0.5f;
            const float g_x1 = gx - gw * 0.5f, g_x2 = gx + gw * 0.5f;
            const float g_y1 = gy - gh * 0.5f, g_y2 = gy + gh * 0.5f;

            const float iw = fmaxf(fminf(p_x2, g_x2) - fmaxf(p_x1, g_x1), 0.0f);
            const float ih = fmaxf(fminf(p_y2, g_y2) - fmaxf(p_y1, g_y1), 0.0f);
            const float inter = iw * ih;
            const float uni   = pw * ph + gw * gh - inter + EPSL;
            const float iou   = inter * frcp(uni);

            const float cw = fmaxf(p_x2, g_x2) - fminf(p_x1, g_x1);
            const float ch = fmaxf(p_y2, g_y2) - fminf(p_y1, g_y1);
            const float c2 = cw * cw + ch * ch + EPSL;
            const float rho2 = (x - gx) * (x - gx) + (y - gy) * (y - gy);

            const float da = atanf(gw * frcp(gh + EPSL))
                           - atanf(pw * frcp(ph + EPSL));
            const float v  = (4.0f / (float)(M_PI * M_PI)) * da * da;
            const float alpha = v * frcp(v - iou + 1.0f + EPSL);

            const float lbox = 1.0f - (iou - (rho2 * frcp(c2) + v * alpha));
            s_iou = m * ts * lbox;
        }

        float vals[4] = { s_xy, s_wh, s_iou, s_conf };
        #pragma unroll
        for (int j = 0; j < 4; ++j) {
            float v = vals[j];
            #pragma unroll
            for (int off = 32; off > 0; off >>= 1)
                v += __shfl_down(v, off, 64);
            vals[j] = v;
        }
        if (lane == 0) {
            #pragma unroll
            for (int j = 0; j < 4; ++j) red[wid][j] = vals[j];
        }
        __syncthreads();
        if (tid == 0) {
            #pragma unroll
            for (int j = 0; j < 4; ++j)
                ws[(size_t)bbid * 4 + j] =
                    red[0][j] + red[1][j] + red[2][j] + red[3][j];
        }
    }
}

// Deterministic final reduction: one block, fixed order -> identical every replay.
__global__ __launch_bounds__(BLK) void yolo_loss_final(
    const float* __restrict__ ws, float* __restrict__ out)
{
    __shared__ float red[4];
    const int lane = threadIdx.x & 63;
    const int wid  = threadIdx.x >> 6;
    const float scale4[4] = { 1.0f / (BSZ * BSZ), 1.0f / (BSZ * BSZ),
                              1.0f / BSZ, 1.0f / BSZ };

    for (int j = 0; j < 4; ++j) {
        float v = 0.f;
        for (int i = threadIdx.x; i < NBLK_BOX; i += BLK)
            v += ws[(size_t)i * 4 + j];
        #pragma unroll
        for (int off = 32; off > 0; off >>= 1)
            v += __shfl_down(v, off, 64);
        if (lane == 0) red[wid] = v;
        __syncthreads();
        if (threadIdx.x == 0)
            out[j] = (red[0] + red[1] + red[2] + red[3]) * scale4[j];
        __syncthreads();
    }
    {
        float v = 0.f;
        for (int i = threadIdx.x; i < NBLK_CLS; i += BLK)
            v += ws[WS_CLS + i];
        #pragma unroll
        for (int off = 32; off > 0; off >>= 1)
            v += __shfl_down(v, off, 64);
        if (lane == 0) red[wid] = v;
        __syncthreads();
        if (threadIdx.x == 0)
            out[4] = (red[0] + red[1] + red[2] + red[3]) * (1.0f / BSZ);
    }
}

extern "C" void kernel_launch(void* const* d_in, const int* in_sizes, int n_in,
                              void* d_out, int out_size, void* d_ws, size_t ws_size,
                              hipStream_t stream) {
    const float* input     = (const float*)d_in[0];
    const float* mask      = (const float*)d_in[1];
    const float* obj_mask  = (const float*)d_in[2];
    const float* tx        = (const float*)d_in[3];
    const float* ty        = (const float*)d_in[4];
    const float* tw        = (const float*)d_in[5];
    const float* th        = (const float*)d_in[6];
    const float* tgt_scale = (const float*)d_in[7];
    const float* tcls      = (const float*)d_in[8];
    float* out = (float*)d_out;
    float* ws  = (float*)d_ws;   // needs (4800 + 4800)*4 = 38400 bytes

    yolo_loss_main<<<NBLK_TOT, BLK, 0, stream>>>(
        input, mask, obj_mask, tx, ty, tw, th, tgt_scale, tcls, ws);
    yolo_loss_final<<<1, BLK, 0, stream>>>(ws, out);
}